// Round 5
// baseline (115.060 us; speedup 1.0000x reference)
//
#include <hip/hip_runtime.h>

// YOLO loss: pred (B,30,7,7) f32, label (B,30,7,7) f32 -> scalar f32 (sum/B).
// Memory-bound: 96.3 MB read once -> ~15.3 us floor @6.3 TB/s (less w/ L3 hits).
//
// Trajectory: R2 showed same-address atomic serialization (4096 atomics = 62us);
// R3->R4 showed waves/CU is the live knob at fixed atomic count (8->16 waves/CU
// = -3.7us). R5: 32 waves/CU (HW max, 8 waves/SIMD; VGPR 44 < 64 so allocatable)
// at the SAME 512 atomics: NT=1024, NB=512 -> 2 blocks/CU x 16 waves.
// Loads stay stride-49 dwords: consecutive-cell lanes -> contiguous ~256 B
// segments per wave-load, fully coalesced; VALUBusy 8% says issue rate is fine.

constexpr int NT = 1024;  // threads per block (16 waves)
constexpr int NB = 512;   // blocks (2 per CU -> 32 waves/CU); 512 atomics total

__device__ __forceinline__ float sq(float x) { return x * x; }

__global__ __launch_bounds__(NT) void yolo_loss_kernel(
    const float* __restrict__ pred, const float* __restrict__ label,
    float* __restrict__ out, int ncells, float inv_B)
{
    const float Gc = 1.0f / 7.0f;
    float acc = 0.0f;

    for (int g = blockIdx.x * NT + threadIdx.x; g < ncells; g += NB * NT) {
        int b = g / 49;
        int s = g - b * 49;
        int i = s / 7;          // axis 2, paired with x
        int j = s - i * 7;      // axis 3, paired with y
        const float* __restrict__ P = pred  + (size_t)b * 1470 + s;
        const float* __restrict__ L = label + (size_t)b * 1470 + s;

        float p[30], l[30];
#pragma unroll
        for (int c = 0; c < 30; ++c) {
            p[c] = P[c * 49];
            l[c] = L[c * 49];
        }

        float fi = (float)i, fj = (float)j;

        // box 1 (pred ch 0..3)
        float cx1 = (p[0] + fi) * Gc, cy1 = (p[1] + fj) * Gc;
        float a_x1 = cx1 - p[2] * 0.5f, a_y1 = cy1 - p[3] * 0.5f;
        float a_x2 = cx1 + p[2] * 0.5f, a_y2 = cy1 + p[3] * 0.5f;
        // box 2 (pred ch 5..8)
        float cx2 = (p[5] + fi) * Gc, cy2 = (p[6] + fj) * Gc;
        float b_x1 = cx2 - p[7] * 0.5f, b_y1 = cy2 - p[8] * 0.5f;
        float b_x2 = cx2 + p[7] * 0.5f, b_y2 = cy2 + p[8] * 0.5f;
        // degenerate label point-box
        float lx = (l[0] + fi) * Gc - l[2] * 0.5f;
        float ly = (l[1] + fj) * Gc - l[3] * 0.5f;

        // iou(box, point-box) — faithful to reference (area_b = 0)
        auto iou_pt = [&](float x1, float y1, float x2, float y2) {
            float ix = fminf(x2, lx) - fmaxf(x1, lx);
            float iy = fminf(y2, ly) - fmaxf(y1, ly);
            float inter = fmaxf(ix, 0.0f) * fmaxf(iy, 0.0f);
            float area_a = (x2 - x1) * (y2 - y1);
            float uni = area_a + 0.0f - inter;
            float denom = (uni == 0.0f) ? 1.0f : uni;
            return inter / denom;
        };

        float iou1 = iou_pt(a_x1, a_y1, a_x2, a_y2);
        float iou2 = iou_pt(b_x1, b_y1, b_x2, b_y2);
        bool sel1 = iou1 > iou2;

        float t1 = sq(p[0] - l[0]) + sq(p[1] - l[1])
                 + sq(sqrtf(p[2]) - sqrtf(l[2])) + sq(sqrtf(p[3]) - sqrtf(l[3]));
        float t2 = sq(p[5] - l[5]) + sq(p[6] - l[6])
                 + sq(sqrtf(p[7]) - sqrtf(l[7])) + sq(sqrtf(p[8]) - sqrtf(l[8]));

        float obj_term     = sel1 ? t1 : t2;
        float conf_term    = sel1 ? sq(p[4] - 1.0f) : sq(p[9] - 1.0f);
        float noobj_obj    = sel1 ? sq(p[9]) : sq(p[4]);
        float noobj_empty  = sq(p[4]) + sq(p[9]);

        float cls = 0.0f;
#pragma unroll
        for (int c = 10; c < 30; ++c) cls += sq(p[c] - l[c]);

        bool obj = (l[4] == 1.0f);
        // obj_weight = 0.5, noobj_weight = 0.5
        acc += obj ? (0.5f * obj_term + conf_term + cls + 0.5f * noobj_obj)
                   : (0.5f * noobj_empty);
    }

    // wave (64-lane) shuffle reduce
#pragma unroll
    for (int off = 32; off > 0; off >>= 1)
        acc += __shfl_down(acc, off, 64);

    __shared__ float swave[NT / 64];
    int lane = threadIdx.x & 63;
    int wid  = threadIdx.x >> 6;
    if (lane == 0) swave[wid] = acc;
    __syncthreads();
    if (threadIdx.x == 0) {
        float bs = 0.0f;
#pragma unroll
        for (int w = 0; w < NT / 64; ++w) bs += swave[w];
        atomicAdd(out, bs * inv_B);   // 512 atomics total, staggered
    }
}

extern "C" void kernel_launch(void* const* d_in, const int* in_sizes, int n_in,
                              void* d_out, int out_size, void* d_ws, size_t ws_size,
                              hipStream_t stream) {
    const float* pred  = (const float*)d_in[0];
    const float* label = (const float*)d_in[1];
    float* out = (float*)d_out;

    int B = in_sizes[0] / 1470;
    int ncells = B * 49;

    hipMemsetAsync(d_out, 0, sizeof(float), stream);

    yolo_loss_kernel<<<NB, NT, 0, stream>>>(pred, label, out, ncells,
                                            1.0f / (float)B);
}

// Round 6
// 114.727 us; speedup vs baseline: 1.0029x; 1.0029x over previous
//
#include <hip/hip_runtime.h>

// YOLO loss: pred (B,30,7,7) f32, label (B,30,7,7) f32 -> scalar f32 (sum/B).
// Memory-bound: 96.3 MB read once; blended L3/HBM floor ~10-15 us for the
// kernel slice. Bench total is dominated by ~95 us of fixed harness traffic
// (ws re-poison 256 MiB @ ~82% HBM peak + input restores) inside the graph.
//
// Tuning trajectory (measured):
//   atomics to one address: 4096 -> 62 us kernel (R2, serialized); 512 ok.
//   waves/CU at 512 atomics: 8 -> 117.4 | 16 -> 113.6 | 32 -> 115.1 total.
// => optimum: NB=512 blocks x NT=512 thr (2 blocks/CU, 16 waves/CU, 512
// staggered per-block atomics). This file is that configuration (best: 113.6).
// Loads are stride-49 dwords: 64 consecutive cells/wave -> contiguous ~196-256 B
// segments, fully coalesced; VALUBusy ~8% -> issue rate not the limiter.

constexpr int NT = 512;   // threads per block (8 waves)
constexpr int NB = 512;   // blocks (2 per CU, 16 waves/CU); 512 atomics total

__device__ __forceinline__ float sq(float x) { return x * x; }

__global__ __launch_bounds__(NT) void yolo_loss_kernel(
    const float* __restrict__ pred, const float* __restrict__ label,
    float* __restrict__ out, int ncells, float inv_B)
{
    const float Gc = 1.0f / 7.0f;
    float acc = 0.0f;

    for (int g = blockIdx.x * NT + threadIdx.x; g < ncells; g += NB * NT) {
        int b = g / 49;
        int s = g - b * 49;
        int i = s / 7;          // axis 2, paired with x
        int j = s - i * 7;      // axis 3, paired with y
        const float* __restrict__ P = pred  + (size_t)b * 1470 + s;
        const float* __restrict__ L = label + (size_t)b * 1470 + s;

        float p[30], l[30];
#pragma unroll
        for (int c = 0; c < 30; ++c) {
            p[c] = P[c * 49];
            l[c] = L[c * 49];
        }

        float fi = (float)i, fj = (float)j;

        // box 1 (pred ch 0..3)
        float cx1 = (p[0] + fi) * Gc, cy1 = (p[1] + fj) * Gc;
        float a_x1 = cx1 - p[2] * 0.5f, a_y1 = cy1 - p[3] * 0.5f;
        float a_x2 = cx1 + p[2] * 0.5f, a_y2 = cy1 + p[3] * 0.5f;
        // box 2 (pred ch 5..8)
        float cx2 = (p[5] + fi) * Gc, cy2 = (p[6] + fj) * Gc;
        float b_x1 = cx2 - p[7] * 0.5f, b_y1 = cy2 - p[8] * 0.5f;
        float b_x2 = cx2 + p[7] * 0.5f, b_y2 = cy2 + p[8] * 0.5f;
        // degenerate label point-box
        float lx = (l[0] + fi) * Gc - l[2] * 0.5f;
        float ly = (l[1] + fj) * Gc - l[3] * 0.5f;

        // iou(box, point-box) — faithful to reference (area_b = 0)
        auto iou_pt = [&](float x1, float y1, float x2, float y2) {
            float ix = fminf(x2, lx) - fmaxf(x1, lx);
            float iy = fminf(y2, ly) - fmaxf(y1, ly);
            float inter = fmaxf(ix, 0.0f) * fmaxf(iy, 0.0f);
            float area_a = (x2 - x1) * (y2 - y1);
            float uni = area_a + 0.0f - inter;
            float denom = (uni == 0.0f) ? 1.0f : uni;
            return inter / denom;
        };

        float iou1 = iou_pt(a_x1, a_y1, a_x2, a_y2);
        float iou2 = iou_pt(b_x1, b_y1, b_x2, b_y2);
        bool sel1 = iou1 > iou2;

        float t1 = sq(p[0] - l[0]) + sq(p[1] - l[1])
                 + sq(sqrtf(p[2]) - sqrtf(l[2])) + sq(sqrtf(p[3]) - sqrtf(l[3]));
        float t2 = sq(p[5] - l[5]) + sq(p[6] - l[6])
                 + sq(sqrtf(p[7]) - sqrtf(l[7])) + sq(sqrtf(p[8]) - sqrtf(l[8]));

        float obj_term     = sel1 ? t1 : t2;
        float conf_term    = sel1 ? sq(p[4] - 1.0f) : sq(p[9] - 1.0f);
        float noobj_obj    = sel1 ? sq(p[9]) : sq(p[4]);
        float noobj_empty  = sq(p[4]) + sq(p[9]);

        float cls = 0.0f;
#pragma unroll
        for (int c = 10; c < 30; ++c) cls += sq(p[c] - l[c]);

        bool obj = (l[4] == 1.0f);
        // obj_weight = 0.5, noobj_weight = 0.5
        acc += obj ? (0.5f * obj_term + conf_term + cls + 0.5f * noobj_obj)
                   : (0.5f * noobj_empty);
    }

    // wave (64-lane) shuffle reduce
#pragma unroll
    for (int off = 32; off > 0; off >>= 1)
        acc += __shfl_down(acc, off, 64);

    __shared__ float swave[NT / 64];
    int lane = threadIdx.x & 63;
    int wid  = threadIdx.x >> 6;
    if (lane == 0) swave[wid] = acc;
    __syncthreads();
    if (threadIdx.x == 0) {
        float bs = 0.0f;
#pragma unroll
        for (int w = 0; w < NT / 64; ++w) bs += swave[w];
        atomicAdd(out, bs * inv_B);   // 512 atomics total, staggered
    }
}

extern "C" void kernel_launch(void* const* d_in, const int* in_sizes, int n_in,
                              void* d_out, int out_size, void* d_ws, size_t ws_size,
                              hipStream_t stream) {
    const float* pred  = (const float*)d_in[0];
    const float* label = (const float*)d_in[1];
    float* out = (float*)d_out;

    int B = in_sizes[0] / 1470;
    int ncells = B * 49;

    hipMemsetAsync(d_out, 0, sizeof(float), stream);

    yolo_loss_kernel<<<NB, NT, 0, stream>>>(pred, label, out, ncells,
                                            1.0f / (float)B);
}